// Round 1
// baseline (19017.004 us; speedup 1.0000x reference)
//
#include <hip/hip_runtime.h>
#include <math.h>

#define N_NODES 40000
#define N_EDGES 640000
#define N_GRAPHS 32
#define HDIM 128
#define NHEADS 4
#define CDIM 32
#define NLAYERS 4
#define ODIM 100

// ---------------------------------------------------------------------------
// float atomic max via int/uint trick (works with 0xFFFFFFFF init sentinel)
__device__ __forceinline__ void atomicMaxFloat(float* addr, float value) {
    if (value >= 0.0f) {
        atomicMax((int*)addr, __float_as_int(value));
    } else {
        atomicMin((unsigned int*)addr, __float_as_uint(value));
    }
}

// ---------------------------------------------------------------------------
// h = x @ node_w + node_b   ([N,4]@[4,128])
__global__ void nodeproj_kernel(const float* __restrict__ x,
                                const float* __restrict__ w,
                                const float* __restrict__ b,
                                float* __restrict__ h) {
    int idx = blockIdx.x * blockDim.x + threadIdx.x;
    if (idx >= N_NODES * HDIM) return;
    int n = idx >> 7, c = idx & 127;
    float s = b[c];
    s += x[n * 4 + 0] * w[0 * HDIM + c];
    s += x[n * 4 + 1] * w[1 * HDIM + c];
    s += x[n * 4 + 2] * w[2 * HDIM + c];
    s += x[n * 4 + 3] * w[3 * HDIM + c];
    h[idx] = s;
}

// ---------------------------------------------------------------------------
// Fold edge_proj into per-layer matrices:
//   Me[i] = edge_w @ We[i]  ([5,128]),  ce[i] = edge_b @ We[i]  ([128])
// grid: NLAYERS*6 blocks of 128 threads (j=0..4 -> Me rows, j=5 -> ce)
__global__ void fold_edge_kernel(const float* __restrict__ edge_w,
                                 const float* __restrict__ edge_b,
                                 const float* __restrict__ We,
                                 float* __restrict__ Me_all,
                                 float* __restrict__ ce_all) {
    int blk = blockIdx.x;
    int i = blk / 6, j = blk % 6;
    int c = threadIdx.x;
    const float* W = We + (size_t)i * HDIM * HDIM;
    float s = 0.0f;
    if (j < 5) {
        for (int k = 0; k < HDIM; ++k) s += edge_w[j * HDIM + k] * W[k * HDIM + c];
        Me_all[i * 5 * HDIM + j * HDIM + c] = s;
    } else {
        for (int k = 0; k < HDIM; ++k) s += edge_b[k] * W[k * HDIM + c];
        ce_all[i * HDIM + c] = s;
    }
}

// ---------------------------------------------------------------------------
// C = A @ B + bias.  A:[M,128], B:[128,128], C:[M,128].  M % 64 == 0.
// Block: 256 threads, 64 rows per block. Thread tile: 4 rows x 8 cols
// (cols strided by 16 so LDS B reads are conflict-free b32).
__global__ __launch_bounds__(256) void gemm128(const float* __restrict__ A,
                                               const float* __restrict__ B,
                                               const float* __restrict__ bias,
                                               float* __restrict__ C, int M) {
    __shared__ float As[64][36];   // +4 pad: a-reads land on distinct banks
    __shared__ float Bs[32][128];
    int tid = threadIdx.x;
    int row0 = blockIdx.x * 64;
    int tx = tid & 15, ty = tid >> 4;
    int r0 = ty * 4;

    float acc[4][8];
#pragma unroll
    for (int r = 0; r < 4; ++r)
#pragma unroll
        for (int j = 0; j < 8; ++j) acc[r][j] = 0.0f;

    for (int kt = 0; kt < 4; ++kt) {
        // A tile 64x32 : 512 float4 loads, 2 per thread, scalar LDS stores
#pragma unroll
        for (int l = 0; l < 2; ++l) {
            int i = tid + l * 256;
            int ar = i >> 3, akc = i & 7;
            float4 av = *(const float4*)(A + (size_t)(row0 + ar) * HDIM + kt * 32 + akc * 4);
            As[ar][akc * 4 + 0] = av.x;
            As[ar][akc * 4 + 1] = av.y;
            As[ar][akc * 4 + 2] = av.z;
            As[ar][akc * 4 + 3] = av.w;
        }
        // B tile 32x128 : 1024 float4, 4 per thread
#pragma unroll
        for (int l = 0; l < 4; ++l) {
            int i = tid + l * 256;
            int br = i >> 5, bc4 = i & 31;
            float4 bv = *(const float4*)(B + (size_t)(kt * 32 + br) * HDIM + bc4 * 4);
            *(float4*)&Bs[br][bc4 * 4] = bv;
        }
        __syncthreads();
#pragma unroll
        for (int kk = 0; kk < 32; ++kk) {
            float a0 = As[r0 + 0][kk];
            float a1 = As[r0 + 1][kk];
            float a2 = As[r0 + 2][kk];
            float a3 = As[r0 + 3][kk];
            float bv[8];
#pragma unroll
            for (int j = 0; j < 8; ++j) bv[j] = Bs[kk][j * 16 + tx];
#pragma unroll
            for (int j = 0; j < 8; ++j) {
                acc[0][j] += a0 * bv[j];
                acc[1][j] += a1 * bv[j];
                acc[2][j] += a2 * bv[j];
                acc[3][j] += a3 * bv[j];
            }
        }
        __syncthreads();
    }
#pragma unroll
    for (int r = 0; r < 4; ++r) {
        int row = row0 + r0 + r;
#pragma unroll
        for (int j = 0; j < 8; ++j) {
            int col = j * 16 + tx;
            C[(size_t)row * HDIM + col] = acc[r][j] + bias[col];
        }
    }
}

// ---------------------------------------------------------------------------
// alpha_raw[e,h] = scale * sum_c q[dst,h,c] * (k[src,h,c] + e_vec[h,c])
// e_vec = edge_attr[e,:] @ Me + ce   (on the fly, Me/ce staged in LDS)
// also atomic-max into mbuf[dst,h]
__global__ __launch_bounds__(256) void alpha_kernel(const int* __restrict__ ei,
                                                    const float* __restrict__ ea,
                                                    const float* __restrict__ q,
                                                    const float* __restrict__ k,
                                                    const float* __restrict__ Me,
                                                    const float* __restrict__ ce,
                                                    float* __restrict__ alpha_raw,
                                                    float* __restrict__ mbuf) {
    __shared__ float sMe[5 * HDIM];
    __shared__ float sce[HDIM];
    for (int i = threadIdx.x; i < 5 * HDIM; i += blockDim.x) sMe[i] = Me[i];
    for (int i = threadIdx.x; i < HDIM; i += blockDim.x) sce[i] = ce[i];
    __syncthreads();

    int idx = blockIdx.x * blockDim.x + threadIdx.x;
    if (idx >= N_EDGES * NHEADS) return;
    int e = idx >> 2, head = idx & 3;
    int src = ei[e], dst = ei[N_EDGES + e];
    float a0 = ea[e * 5 + 0], a1 = ea[e * 5 + 1], a2 = ea[e * 5 + 2];
    float a3 = ea[e * 5 + 3], a4 = ea[e * 5 + 4];
    const float* qd = q + (size_t)dst * HDIM + head * CDIM;
    const float* ks = k + (size_t)src * HDIM + head * CDIM;
    float s = 0.0f;
#pragma unroll
    for (int c = 0; c < CDIM; ++c) {
        int ch = head * CDIM + c;
        float ev = sce[ch] + a0 * sMe[0 * HDIM + ch] + a1 * sMe[1 * HDIM + ch] +
                   a2 * sMe[2 * HDIM + ch] + a3 * sMe[3 * HDIM + ch] + a4 * sMe[4 * HDIM + ch];
        s += qd[c] * (ks[c] + ev);
    }
    s *= 0.17677669529663687f;  // 1/sqrt(32)
    alpha_raw[idx] = s;
    atomicMaxFloat(&mbuf[dst * NHEADS + head], s);
}

// ---------------------------------------------------------------------------
// alpha[idx] = exp(alpha_raw - m[dst,h]);  ssum[dst,h] += alpha
__global__ void expsum_kernel(const int* __restrict__ ei,
                              const float* __restrict__ mbuf,
                              float* __restrict__ alpha,
                              float* __restrict__ ssum) {
    int idx = blockIdx.x * blockDim.x + threadIdx.x;
    if (idx >= N_EDGES * NHEADS) return;
    int e = idx >> 2, head = idx & 3;
    int dst = ei[N_EDGES + e];
    float p = expf(alpha[idx] - mbuf[dst * NHEADS + head]);
    alpha[idx] = p;
    atomicAdd(&ssum[dst * NHEADS + head], p);
}

// ---------------------------------------------------------------------------
// out[dst,h,c] += (alpha/(ssum+1e-16)) * (v[src,h,c] + e_vec[h,c])
// (out buffer already holds the skip projection h@Wskip+bskip)
__global__ __launch_bounds__(256) void message_kernel(const int* __restrict__ ei,
                                                      const float* __restrict__ ea,
                                                      const float* __restrict__ v,
                                                      const float* __restrict__ Me,
                                                      const float* __restrict__ ce,
                                                      const float* __restrict__ alpha,
                                                      const float* __restrict__ ssum,
                                                      float* __restrict__ out) {
    __shared__ float sMe[5 * HDIM];
    __shared__ float sce[HDIM];
    for (int i = threadIdx.x; i < 5 * HDIM; i += blockDim.x) sMe[i] = Me[i];
    for (int i = threadIdx.x; i < HDIM; i += blockDim.x) sce[i] = ce[i];
    __syncthreads();

    int idx = blockIdx.x * blockDim.x + threadIdx.x;
    if (idx >= N_EDGES * NHEADS) return;
    int e = idx >> 2, head = idx & 3;
    int src = ei[e], dst = ei[N_EDGES + e];
    float p = alpha[idx] / (ssum[dst * NHEADS + head] + 1e-16f);
    float a0 = ea[e * 5 + 0], a1 = ea[e * 5 + 1], a2 = ea[e * 5 + 2];
    float a3 = ea[e * 5 + 3], a4 = ea[e * 5 + 4];
    const float* vs = v + (size_t)src * HDIM + head * CDIM;
    float* od = out + (size_t)dst * HDIM + head * CDIM;
#pragma unroll
    for (int c = 0; c < CDIM; ++c) {
        int ch = head * CDIM + c;
        float ev = sce[ch] + a0 * sMe[0 * HDIM + ch] + a1 * sMe[1 * HDIM + ch] +
                   a2 * sMe[2 * HDIM + ch] + a3 * sMe[3 * HDIM + ch] + a4 * sMe[4 * HDIM + ch];
        atomicAdd(&od[c], p * (vs[c] + ev));
    }
}

// ---------------------------------------------------------------------------
// h = relu(layernorm(out) * g + b)   one block (128 threads) per node
__global__ void ln_relu_kernel(const float* __restrict__ ob,
                               const float* __restrict__ g,
                               const float* __restrict__ b,
                               float* __restrict__ h) {
    int n = blockIdx.x, c = threadIdx.x;
    float val = ob[(size_t)n * HDIM + c];
    __shared__ float red[HDIM];
    red[c] = val;
    __syncthreads();
    for (int s = 64; s > 0; s >>= 1) {
        if (c < s) red[c] += red[c + s];
        __syncthreads();
    }
    float mu = red[0] * (1.0f / HDIM);
    __syncthreads();
    float d = val - mu;
    red[c] = d * d;
    __syncthreads();
    for (int s = 64; s > 0; s >>= 1) {
        if (c < s) red[c] += red[c + s];
        __syncthreads();
    }
    float var = red[0] * (1.0f / HDIM);
    float y = d * rsqrtf(var + 1e-5f) * g[c] + b[c];
    h[(size_t)n * HDIM + c] = fmaxf(y, 0.0f);
}

// ---------------------------------------------------------------------------
// mean-pool per graph: pool[g,c] += h[n,c]; cnt[g] += 1
__global__ void pool_kernel(const float* __restrict__ h,
                            const int* __restrict__ batch,
                            float* __restrict__ pool,
                            float* __restrict__ cnt) {
    int idx = blockIdx.x * blockDim.x + threadIdx.x;
    if (idx >= N_NODES * HDIM) return;
    int n = idx >> 7, c = idx & 127;
    int g = batch[n];
    atomicAdd(&pool[g * HDIM + c], h[idx]);
    if (c == 0) atomicAdd(&cnt[g], 1.0f);
}

// ---------------------------------------------------------------------------
// both MLP heads; one block (128 threads) per graph
__global__ void heads_kernel(const float* __restrict__ pool,
                             const float* __restrict__ cnt,
                             const float* __restrict__ dw1, const float* __restrict__ db1,
                             const float* __restrict__ dw2, const float* __restrict__ db2,
                             const float* __restrict__ tw1, const float* __restrict__ tb1,
                             const float* __restrict__ tw2, const float* __restrict__ tb2,
                             float* __restrict__ outp) {
    int g = blockIdx.x, t = threadIdx.x;
    __shared__ float hg[HDIM];
    __shared__ float hid[64];
    float c = fmaxf(cnt[g], 1.0f);
    hg[t] = pool[g * HDIM + t] / c;
    __syncthreads();
    if (t < 64) {
        float s = db1[t];
        for (int i = 0; i < HDIM; ++i) s += hg[i] * dw1[i * 64 + t];
        hid[t] = fmaxf(s, 0.0f);
    }
    __syncthreads();
    if (t < ODIM) {
        float s = db2[t];
        for (int j = 0; j < 64; ++j) s += hid[j] * dw2[j * ODIM + t];
        outp[g * ODIM + t] = s;
    }
    __syncthreads();
    if (t < 64) {
        float s = tb1[t];
        for (int i = 0; i < HDIM; ++i) s += hg[i] * tw1[i * 64 + t];
        hid[t] = fmaxf(s, 0.0f);
    }
    __syncthreads();
    if (t < ODIM) {
        float s = tb2[t];
        for (int j = 0; j < 64; ++j) s += hid[j] * tw2[j * ODIM + t];
        outp[N_GRAPHS * ODIM + g * ODIM + t] = s;
    }
}

// ---------------------------------------------------------------------------
extern "C" void kernel_launch(void* const* d_in, const int* in_sizes, int n_in,
                              void* d_out, int out_size, void* d_ws, size_t ws_size,
                              hipStream_t stream) {
    const float* x        = (const float*)d_in[0];
    const float* ea       = (const float*)d_in[1];
    const float* node_w   = (const float*)d_in[2];
    const float* node_b   = (const float*)d_in[3];
    const float* edge_w   = (const float*)d_in[4];
    const float* edge_b   = (const float*)d_in[5];
    const float* Wq       = (const float*)d_in[6];
    const float* bq       = (const float*)d_in[7];
    const float* Wk       = (const float*)d_in[8];
    const float* bk       = (const float*)d_in[9];
    const float* Wv       = (const float*)d_in[10];
    const float* bv       = (const float*)d_in[11];
    // d_in[12] = We (folded via fold_edge_kernel)
    const float* We       = (const float*)d_in[12];
    const float* Wskip    = (const float*)d_in[13];
    const float* bskip    = (const float*)d_in[14];
    const float* ln_g     = (const float*)d_in[15];
    const float* ln_b     = (const float*)d_in[16];
    const float* dw1      = (const float*)d_in[17];
    const float* db1      = (const float*)d_in[18];
    const float* dw2      = (const float*)d_in[19];
    const float* db2      = (const float*)d_in[20];
    const float* tw1      = (const float*)d_in[21];
    const float* tb1      = (const float*)d_in[22];
    const float* tw2      = (const float*)d_in[23];
    const float* tb2      = (const float*)d_in[24];
    const int*   ei       = (const int*)d_in[25];
    const int*   batch    = (const int*)d_in[26];
    float* out = (float*)d_out;

    float* ws = (float*)d_ws;
    size_t off = 0;
    float* h      = ws + off; off += (size_t)N_NODES * HDIM;
    float* q      = ws + off; off += (size_t)N_NODES * HDIM;
    float* k      = ws + off; off += (size_t)N_NODES * HDIM;
    float* v      = ws + off; off += (size_t)N_NODES * HDIM;
    float* ob     = ws + off; off += (size_t)N_NODES * HDIM;   // skip + messages
    float* alpha  = ws + off; off += (size_t)N_EDGES * NHEADS;
    float* mbuf   = ws + off; off += (size_t)N_NODES * NHEADS;
    float* ssum   = ws + off; off += (size_t)N_NODES * NHEADS;
    float* Me_all = ws + off; off += NLAYERS * 5 * HDIM;
    float* ce_all = ws + off; off += NLAYERS * HDIM;
    float* pool   = ws + off; off += N_GRAPHS * HDIM;
    float* cnt    = ws + off; off += N_GRAPHS;
    (void)in_sizes; (void)n_in; (void)out_size; (void)ws_size;

    const int nthreads = 256;
    const int eh_blocks = (N_EDGES * NHEADS) / nthreads;       // exact: 10000
    const int nc_blocks = (N_NODES * HDIM) / nthreads;         // exact: 20000
    const int gemm_blocks = N_NODES / 64;                      // exact: 625

    nodeproj_kernel<<<nc_blocks, nthreads, 0, stream>>>(x, node_w, node_b, h);
    fold_edge_kernel<<<NLAYERS * 6, HDIM, 0, stream>>>(edge_w, edge_b, We, Me_all, ce_all);

    for (int i = 0; i < NLAYERS; ++i) {
        const float* Me = Me_all + i * 5 * HDIM;
        const float* ce = ce_all + i * HDIM;
        gemm128<<<gemm_blocks, 256, 0, stream>>>(h, Wq + (size_t)i * HDIM * HDIM, bq + i * HDIM, q, N_NODES);
        gemm128<<<gemm_blocks, 256, 0, stream>>>(h, Wk + (size_t)i * HDIM * HDIM, bk + i * HDIM, k, N_NODES);
        gemm128<<<gemm_blocks, 256, 0, stream>>>(h, Wv + (size_t)i * HDIM * HDIM, bv + i * HDIM, v, N_NODES);
        gemm128<<<gemm_blocks, 256, 0, stream>>>(h, Wskip + (size_t)i * HDIM * HDIM, bskip + i * HDIM, ob, N_NODES);
        hipMemsetAsync(mbuf, 0xFF, (size_t)N_NODES * NHEADS * sizeof(float), stream);  // -NaN sentinel
        hipMemsetAsync(ssum, 0x00, (size_t)N_NODES * NHEADS * sizeof(float), stream);
        alpha_kernel<<<eh_blocks, nthreads, 0, stream>>>(ei, ea, q, k, Me, ce, alpha, mbuf);
        expsum_kernel<<<eh_blocks, nthreads, 0, stream>>>(ei, mbuf, alpha, ssum);
        message_kernel<<<eh_blocks, nthreads, 0, stream>>>(ei, ea, v, Me, ce, alpha, ssum, ob);
        ln_relu_kernel<<<N_NODES, HDIM, 0, stream>>>(ob, ln_g + i * HDIM, ln_b + i * HDIM, h);
    }

    hipMemsetAsync(pool, 0x00, (size_t)(N_GRAPHS * HDIM + N_GRAPHS) * sizeof(float), stream);
    pool_kernel<<<nc_blocks, nthreads, 0, stream>>>(h, batch, pool, cnt);
    heads_kernel<<<N_GRAPHS, HDIM, 0, stream>>>(pool, cnt, dw1, db1, dw2, db2,
                                                tw1, tb1, tw2, tb2, out);
}

// Round 2
// 1683.882 us; speedup vs baseline: 11.2936x; 11.2936x over previous
//
#include <hip/hip_runtime.h>
#include <math.h>

#define N_NODES 40000
#define N_EDGES 640000
#define N_GRAPHS 32
#define HDIM 128
#define NHEADS 4
#define CDIM 32
#define NLAYERS 4
#define ODIM 100
#define SCAN_B 256
#define SCAN_NBLK ((N_NODES + SCAN_B - 1) / SCAN_B)   // 157

// ---------------------------------------------------------------------------
// h = x @ node_w + node_b   ([N,4]@[4,128])
__global__ void nodeproj_kernel(const float* __restrict__ x,
                                const float* __restrict__ w,
                                const float* __restrict__ b,
                                float* __restrict__ h) {
    int idx = blockIdx.x * blockDim.x + threadIdx.x;
    if (idx >= N_NODES * HDIM) return;
    int n = idx >> 7, c = idx & 127;
    float s = b[c];
    s += x[n * 4 + 0] * w[0 * HDIM + c];
    s += x[n * 4 + 1] * w[1 * HDIM + c];
    s += x[n * 4 + 2] * w[2 * HDIM + c];
    s += x[n * 4 + 3] * w[3 * HDIM + c];
    h[idx] = s;
}

// ---------------------------------------------------------------------------
// Fold edge_proj into per-layer matrices:
//   Me[i] = edge_w @ We[i]  ([5,128]),  ce[i] = edge_b @ We[i]  ([128])
__global__ void fold_edge_kernel(const float* __restrict__ edge_w,
                                 const float* __restrict__ edge_b,
                                 const float* __restrict__ We,
                                 float* __restrict__ Me_all,
                                 float* __restrict__ ce_all) {
    int blk = blockIdx.x;
    int i = blk / 6, j = blk % 6;
    int c = threadIdx.x;
    const float* W = We + (size_t)i * HDIM * HDIM;
    float s = 0.0f;
    if (j < 5) {
        for (int k = 0; k < HDIM; ++k) s += edge_w[j * HDIM + k] * W[k * HDIM + c];
        Me_all[i * 5 * HDIM + j * HDIM + c] = s;
    } else {
        for (int k = 0; k < HDIM; ++k) s += edge_b[k] * W[k * HDIM + c];
        ce_all[i * HDIM + c] = s;
    }
}

// ---------------------------------------------------------------------------
// CSR build: count in-degree, 2-level exclusive scan, scatter (e,src) by dst
__global__ void count_deg_kernel(const int* __restrict__ ei, int* __restrict__ deg) {
    int e = blockIdx.x * blockDim.x + threadIdx.x;
    if (e >= N_EDGES) return;
    atomicAdd(&deg[ei[N_EDGES + e]], 1);
}

__global__ void scan1_kernel(const int* __restrict__ deg,
                             int* __restrict__ rowptr, int* __restrict__ bsum) {
    __shared__ int sd[SCAN_B];
    int tid = threadIdx.x;
    int i = blockIdx.x * SCAN_B + tid;
    int v = (i < N_NODES) ? deg[i] : 0;
    sd[tid] = v;
    __syncthreads();
#pragma unroll
    for (int off = 1; off < SCAN_B; off <<= 1) {
        int tmp = (tid >= off) ? sd[tid - off] : 0;
        __syncthreads();
        sd[tid] += tmp;
        __syncthreads();
    }
    if (i < N_NODES) rowptr[i] = sd[tid] - v;          // exclusive within block
    if (tid == SCAN_B - 1) bsum[blockIdx.x] = sd[tid]; // block total
}

__global__ void scan2_kernel(const int* __restrict__ bsum, int* __restrict__ bscan) {
    __shared__ int sd[SCAN_B];
    int tid = threadIdx.x;
    int v = (tid < SCAN_NBLK) ? bsum[tid] : 0;
    sd[tid] = v;
    __syncthreads();
#pragma unroll
    for (int off = 1; off < SCAN_B; off <<= 1) {
        int tmp = (tid >= off) ? sd[tid - off] : 0;
        __syncthreads();
        sd[tid] += tmp;
        __syncthreads();
    }
    if (tid < SCAN_NBLK) bscan[tid] = sd[tid] - v;     // exclusive
}

__global__ void scan3_kernel(int* __restrict__ rowptr, const int* __restrict__ bscan) {
    int i = blockIdx.x * SCAN_B + threadIdx.x;
    if (i < N_NODES) rowptr[i] += bscan[blockIdx.x];
    if (i == 0) rowptr[N_NODES] = N_EDGES;
}

__global__ void fill_csr_kernel(const int* __restrict__ ei,
                                const int* __restrict__ rowptr,
                                int* __restrict__ cursor,
                                int2* __restrict__ srt) {
    int e = blockIdx.x * blockDim.x + threadIdx.x;
    if (e >= N_EDGES) return;
    int src = ei[e], dst = ei[N_EDGES + e];
    int pos = atomicAdd(&cursor[dst], 1);
    srt[rowptr[dst] + pos] = make_int2(e, src);
}

// ---------------------------------------------------------------------------
// C = A @ B + bias.  A:[M,128], B:[128,128], C:[M,128].  M % 64 == 0.
__global__ __launch_bounds__(256) void gemm128(const float* __restrict__ A,
                                               const float* __restrict__ B,
                                               const float* __restrict__ bias,
                                               float* __restrict__ C, int M) {
    __shared__ float As[64][36];
    __shared__ float Bs[32][128];
    int tid = threadIdx.x;
    int row0 = blockIdx.x * 64;
    int tx = tid & 15, ty = tid >> 4;
    int r0 = ty * 4;

    float acc[4][8];
#pragma unroll
    for (int r = 0; r < 4; ++r)
#pragma unroll
        for (int j = 0; j < 8; ++j) acc[r][j] = 0.0f;

    for (int kt = 0; kt < 4; ++kt) {
#pragma unroll
        for (int l = 0; l < 2; ++l) {
            int i = tid + l * 256;
            int ar = i >> 3, akc = i & 7;
            float4 av = *(const float4*)(A + (size_t)(row0 + ar) * HDIM + kt * 32 + akc * 4);
            As[ar][akc * 4 + 0] = av.x;
            As[ar][akc * 4 + 1] = av.y;
            As[ar][akc * 4 + 2] = av.z;
            As[ar][akc * 4 + 3] = av.w;
        }
#pragma unroll
        for (int l = 0; l < 4; ++l) {
            int i = tid + l * 256;
            int br = i >> 5, bc4 = i & 31;
            float4 bv = *(const float4*)(B + (size_t)(kt * 32 + br) * HDIM + bc4 * 4);
            *(float4*)&Bs[br][bc4 * 4] = bv;
        }
        __syncthreads();
#pragma unroll
        for (int kk = 0; kk < 32; ++kk) {
            float a0 = As[r0 + 0][kk];
            float a1 = As[r0 + 1][kk];
            float a2 = As[r0 + 2][kk];
            float a3 = As[r0 + 3][kk];
            float bv[8];
#pragma unroll
            for (int j = 0; j < 8; ++j) bv[j] = Bs[kk][j * 16 + tx];
#pragma unroll
            for (int j = 0; j < 8; ++j) {
                acc[0][j] += a0 * bv[j];
                acc[1][j] += a1 * bv[j];
                acc[2][j] += a2 * bv[j];
                acc[3][j] += a3 * bv[j];
            }
        }
        __syncthreads();
    }
#pragma unroll
    for (int r = 0; r < 4; ++r) {
        int row = row0 + r0 + r;
#pragma unroll
        for (int j = 0; j < 8; ++j) {
            int col = j * 16 + tx;
            C[(size_t)row * HDIM + col] = acc[r][j] + bias[col];
        }
    }
}

// ---------------------------------------------------------------------------
// Fused per-dst-node attention aggregation + skip + LayerNorm + ReLU.
// One block (128 threads = 2 waves) per node; thread t owns channel t
// (head = t>>5). Online softmax over the node's CSR edge list.
__global__ __launch_bounds__(128) void agg_kernel(
    const int2* __restrict__ srt, const int* __restrict__ rowptr,
    const float* __restrict__ ea,
    const float* __restrict__ q, const float* __restrict__ k,
    const float* __restrict__ v,
    const float* __restrict__ Me, const float* __restrict__ ce,
    const float* __restrict__ skip,
    const float* __restrict__ lg, const float* __restrict__ lb,
    float* __restrict__ hout) {
    __shared__ float sMe[5 * HDIM];
    __shared__ float wred[2];
    int n = blockIdx.x;
    int t = threadIdx.x;
    for (int i = t; i < 5 * HDIM; i += 128) sMe[i] = Me[i];
    float cer = ce[t];
    // fold 1/sqrt(C) into q
    float qv = q[(size_t)n * HDIM + t] * 0.17677669529663687f;
    __syncthreads();

    int beg = rowptr[n], end = rowptr[n + 1];
    float m = -INFINITY, l = 0.0f, o = 0.0f;
    for (int idx = beg; idx < end; ++idx) {
        int2 es = srt[idx];
        int e = es.x, src = es.y;
        float a0 = ea[e * 5 + 0], a1 = ea[e * 5 + 1], a2 = ea[e * 5 + 2];
        float a3 = ea[e * 5 + 3], a4 = ea[e * 5 + 4];
        float ev = cer + a0 * sMe[t] + a1 * sMe[HDIM + t] + a2 * sMe[2 * HDIM + t] +
                   a3 * sMe[3 * HDIM + t] + a4 * sMe[4 * HDIM + t];
        float kj = k[(size_t)src * HDIM + t] + ev;
        float p = qv * kj;
        // sum over the 32 channels of this head (32-lane butterfly)
        p += __shfl_xor(p, 16, 32);
        p += __shfl_xor(p, 8, 32);
        p += __shfl_xor(p, 4, 32);
        p += __shfl_xor(p, 2, 32);
        p += __shfl_xor(p, 1, 32);
        float a = p;
        float m_new = fmaxf(m, a);
        float sc = __expf(m - m_new);   // 0 on first edge (m = -inf)
        float pe = __expf(a - m_new);
        float vj = v[(size_t)src * HDIM + t] + ev;
        o = o * sc + pe * vj;
        l = l * sc + pe;
        m = m_new;
    }
    float msg = o / (l + 1e-16f);       // 0 for isolated nodes
    float val = skip[(size_t)n * HDIM + t] + msg;

    // LayerNorm over 128 channels: wave butterfly + LDS combine of 2 waves
    float s = val;
#pragma unroll
    for (int mask = 32; mask >= 1; mask >>= 1) s += __shfl_xor(s, mask, 64);
    if ((t & 63) == 0) wred[t >> 6] = s;
    __syncthreads();
    float mu = (wred[0] + wred[1]) * (1.0f / HDIM);
    float d = val - mu;
    float s2 = d * d;
#pragma unroll
    for (int mask = 32; mask >= 1; mask >>= 1) s2 += __shfl_xor(s2, mask, 64);
    __syncthreads();
    if ((t & 63) == 0) wred[t >> 6] = s2;
    __syncthreads();
    float var = (wred[0] + wred[1]) * (1.0f / HDIM);
    float y = d * rsqrtf(var + 1e-5f) * lg[t] + lb[t];
    hout[(size_t)n * HDIM + t] = fmaxf(y, 0.0f);
}

// ---------------------------------------------------------------------------
__global__ void pool_kernel(const float* __restrict__ h,
                            const int* __restrict__ batch,
                            float* __restrict__ pool,
                            float* __restrict__ cnt) {
    int idx = blockIdx.x * blockDim.x + threadIdx.x;
    if (idx >= N_NODES * HDIM) return;
    int n = idx >> 7, c = idx & 127;
    int g = batch[n];
    atomicAdd(&pool[g * HDIM + c], h[idx]);
    if (c == 0) atomicAdd(&cnt[g], 1.0f);
}

// ---------------------------------------------------------------------------
__global__ void heads_kernel(const float* __restrict__ pool,
                             const float* __restrict__ cnt,
                             const float* __restrict__ dw1, const float* __restrict__ db1,
                             const float* __restrict__ dw2, const float* __restrict__ db2,
                             const float* __restrict__ tw1, const float* __restrict__ tb1,
                             const float* __restrict__ tw2, const float* __restrict__ tb2,
                             float* __restrict__ outp) {
    int g = blockIdx.x, t = threadIdx.x;
    __shared__ float hg[HDIM];
    __shared__ float hid[64];
    float c = fmaxf(cnt[g], 1.0f);
    hg[t] = pool[g * HDIM + t] / c;
    __syncthreads();
    if (t < 64) {
        float s = db1[t];
        for (int i = 0; i < HDIM; ++i) s += hg[i] * dw1[i * 64 + t];
        hid[t] = fmaxf(s, 0.0f);
    }
    __syncthreads();
    if (t < ODIM) {
        float s = db2[t];
        for (int j = 0; j < 64; ++j) s += hid[j] * dw2[j * ODIM + t];
        outp[g * ODIM + t] = s;
    }
    __syncthreads();
    if (t < 64) {
        float s = tb1[t];
        for (int i = 0; i < HDIM; ++i) s += hg[i] * tw1[i * 64 + t];
        hid[t] = fmaxf(s, 0.0f);
    }
    __syncthreads();
    if (t < ODIM) {
        float s = tb2[t];
        for (int j = 0; j < 64; ++j) s += hid[j] * tw2[j * ODIM + t];
        outp[N_GRAPHS * ODIM + g * ODIM + t] = s;
    }
}

// ---------------------------------------------------------------------------
extern "C" void kernel_launch(void* const* d_in, const int* in_sizes, int n_in,
                              void* d_out, int out_size, void* d_ws, size_t ws_size,
                              hipStream_t stream) {
    const float* x        = (const float*)d_in[0];
    const float* ea       = (const float*)d_in[1];
    const float* node_w   = (const float*)d_in[2];
    const float* node_b   = (const float*)d_in[3];
    const float* edge_w   = (const float*)d_in[4];
    const float* edge_b   = (const float*)d_in[5];
    const float* Wq       = (const float*)d_in[6];
    const float* bq       = (const float*)d_in[7];
    const float* Wk       = (const float*)d_in[8];
    const float* bk       = (const float*)d_in[9];
    const float* Wv       = (const float*)d_in[10];
    const float* bv       = (const float*)d_in[11];
    const float* We       = (const float*)d_in[12];
    const float* Wskip    = (const float*)d_in[13];
    const float* bskip    = (const float*)d_in[14];
    const float* ln_g     = (const float*)d_in[15];
    const float* ln_b     = (const float*)d_in[16];
    const float* dw1      = (const float*)d_in[17];
    const float* db1      = (const float*)d_in[18];
    const float* dw2      = (const float*)d_in[19];
    const float* db2      = (const float*)d_in[20];
    const float* tw1      = (const float*)d_in[21];
    const float* tb1      = (const float*)d_in[22];
    const float* tw2      = (const float*)d_in[23];
    const float* tb2      = (const float*)d_in[24];
    const int*   ei       = (const int*)d_in[25];
    const int*   batch    = (const int*)d_in[26];
    float* out = (float*)d_out;
    (void)in_sizes; (void)n_in; (void)out_size; (void)ws_size;

    // ---- workspace carve (byte offsets, 256B aligned) ----
    char* wsb = (char*)d_ws;
    size_t off = 0;
    auto carve = [&](size_t bytes) -> void* {
        void* p = wsb + off;
        off += (bytes + 255) & ~(size_t)255;
        return p;
    };
    float* h      = (float*)carve((size_t)N_NODES * HDIM * 4);
    float* q      = (float*)carve((size_t)N_NODES * HDIM * 4);
    float* k      = (float*)carve((size_t)N_NODES * HDIM * 4);
    float* v      = (float*)carve((size_t)N_NODES * HDIM * 4);
    float* ob     = (float*)carve((size_t)N_NODES * HDIM * 4);   // skip buffer
    int2*  srt    = (int2*) carve((size_t)N_EDGES * 8);
    int*   deg    = (int*)  carve((size_t)N_NODES * 4);
    int*   rowptr = (int*)  carve((size_t)(N_NODES + 1) * 4);
    int*   cursor = (int*)  carve((size_t)N_NODES * 4);
    int*   bsum   = (int*)  carve((size_t)SCAN_NBLK * 4);
    int*   bscan  = (int*)  carve((size_t)SCAN_NBLK * 4);
    float* Me_all = (float*)carve((size_t)NLAYERS * 5 * HDIM * 4);
    float* ce_all = (float*)carve((size_t)NLAYERS * HDIM * 4);
    float* pool   = (float*)carve((size_t)N_GRAPHS * HDIM * 4);
    float* cnt    = (float*)carve((size_t)N_GRAPHS * 4);

    const int nthreads = 256;
    const int e_blocks  = (N_EDGES + nthreads - 1) / nthreads;
    const int nc_blocks = (N_NODES * HDIM) / nthreads;
    const int gemm_blocks = N_NODES / 64;

    // ---- CSR build (edge_index is an input; rebuilt each call) ----
    hipMemsetAsync(deg, 0, (size_t)N_NODES * 4, stream);
    hipMemsetAsync(cursor, 0, (size_t)N_NODES * 4, stream);
    count_deg_kernel<<<e_blocks, nthreads, 0, stream>>>(ei, deg);
    scan1_kernel<<<SCAN_NBLK, SCAN_B, 0, stream>>>(deg, rowptr, bsum);
    scan2_kernel<<<1, SCAN_B, 0, stream>>>(bsum, bscan);
    scan3_kernel<<<SCAN_NBLK, SCAN_B, 0, stream>>>(rowptr, bscan);
    fill_csr_kernel<<<e_blocks, nthreads, 0, stream>>>(ei, rowptr, cursor, srt);

    // ---- projections ----
    nodeproj_kernel<<<nc_blocks, nthreads, 0, stream>>>(x, node_w, node_b, h);
    fold_edge_kernel<<<NLAYERS * 6, HDIM, 0, stream>>>(edge_w, edge_b, We, Me_all, ce_all);

    for (int i = 0; i < NLAYERS; ++i) {
        const float* Me = Me_all + i * 5 * HDIM;
        const float* ce = ce_all + i * HDIM;
        gemm128<<<gemm_blocks, 256, 0, stream>>>(h, Wq + (size_t)i * HDIM * HDIM, bq + i * HDIM, q, N_NODES);
        gemm128<<<gemm_blocks, 256, 0, stream>>>(h, Wk + (size_t)i * HDIM * HDIM, bk + i * HDIM, k, N_NODES);
        gemm128<<<gemm_blocks, 256, 0, stream>>>(h, Wv + (size_t)i * HDIM * HDIM, bv + i * HDIM, v, N_NODES);
        gemm128<<<gemm_blocks, 256, 0, stream>>>(h, Wskip + (size_t)i * HDIM * HDIM, bskip + i * HDIM, ob, N_NODES);
        agg_kernel<<<N_NODES, 128, 0, stream>>>(srt, rowptr, ea, q, k, v, Me, ce, ob,
                                                ln_g + i * HDIM, ln_b + i * HDIM, h);
    }

    hipMemsetAsync(pool, 0, (size_t)N_GRAPHS * HDIM * 4, stream);
    hipMemsetAsync(cnt, 0, (size_t)N_GRAPHS * 4, stream);
    pool_kernel<<<nc_blocks, nthreads, 0, stream>>>(h, batch, pool, cnt);
    heads_kernel<<<N_GRAPHS, HDIM, 0, stream>>>(pool, cnt, dw1, db1, dw2, db2,
                                                tw1, tb1, tw2, tb2, out);
}

// Round 3
// 980.935 us; speedup vs baseline: 19.3866x; 1.7166x over previous
//
#include <hip/hip_runtime.h>
#include <math.h>

#define N_NODES 40000
#define N_EDGES 640000
#define N_GRAPHS 32
#define HDIM 128
#define NHEADS 4
#define CDIM 32
#define NLAYERS 4
#define ODIM 100
#define SCAN_B 256
#define SCAN_NBLK ((N_NODES + SCAN_B - 1) / SCAN_B)   // 157
#define M_PAD 40064                                   // 313 * 128
#define POOL_CHUNK 256
#define POOL_NBLK ((N_NODES + POOL_CHUNK - 1) / POOL_CHUNK)  // 157

typedef __bf16 bf16_t;
typedef bf16_t bf16x8 __attribute__((ext_vector_type(8)));
typedef float f32x4 __attribute__((ext_vector_type(4)));

// ---------------------------------------------------------------------------
// h = x @ node_w + node_b   ([N,4]@[4,128]); also emit bf16 copy for MFMA
__global__ void nodeproj_kernel(const float* __restrict__ x,
                                const float* __restrict__ w,
                                const float* __restrict__ b,
                                float* __restrict__ h,
                                bf16_t* __restrict__ hb) {
    int idx = blockIdx.x * blockDim.x + threadIdx.x;
    if (idx >= N_NODES * HDIM) return;
    int n = idx >> 7, c = idx & 127;
    float s = b[c];
    s += x[n * 4 + 0] * w[0 * HDIM + c];
    s += x[n * 4 + 1] * w[1 * HDIM + c];
    s += x[n * 4 + 2] * w[2 * HDIM + c];
    s += x[n * 4 + 3] * w[3 * HDIM + c];
    h[idx] = s;
    hb[idx] = (bf16_t)s;
}

// ---------------------------------------------------------------------------
// Fold edge_proj into per-layer matrices:
//   Me[i] = edge_w @ We[i]  ([5,128]),  ce[i] = edge_b @ We[i]  ([128])
__global__ void fold_edge_kernel(const float* __restrict__ edge_w,
                                 const float* __restrict__ edge_b,
                                 const float* __restrict__ We,
                                 float* __restrict__ Me_all,
                                 float* __restrict__ ce_all) {
    int blk = blockIdx.x;
    int i = blk / 6, j = blk % 6;
    int c = threadIdx.x;
    const float* W = We + (size_t)i * HDIM * HDIM;
    float s = 0.0f;
    if (j < 5) {
        for (int k = 0; k < HDIM; ++k) s += edge_w[j * HDIM + k] * W[k * HDIM + c];
        Me_all[i * 5 * HDIM + j * HDIM + c] = s;
    } else {
        for (int k = 0; k < HDIM; ++k) s += edge_b[k] * W[k * HDIM + c];
        ce_all[i * HDIM + c] = s;
    }
}

// ---------------------------------------------------------------------------
// Convert all layer weights to bf16, transposed to [n][k] for MFMA B-frags.
// grid: NLAYERS*4*128 blocks x 128 threads;  block -> (layer, mat, n), thread -> k
__global__ void convert_w_kernel(const float* __restrict__ Wq, const float* __restrict__ Wk,
                                 const float* __restrict__ Wv, const float* __restrict__ Ws,
                                 bf16_t* __restrict__ Wtb) {
    int b = blockIdx.x;
    int n = b & 127;
    int matli = b >> 7;
    int mat = matli & 3, li = matli >> 2;
    int kk = threadIdx.x;
    const float* W = (mat == 0 ? Wq : mat == 1 ? Wk : mat == 2 ? Wv : Ws) + (size_t)li * HDIM * HDIM;
    Wtb[((size_t)(li * 4 + mat) * HDIM + n) * HDIM + kk] = (bf16_t)W[kk * HDIM + n];
}

// ---------------------------------------------------------------------------
// CSR build: count in-degree, 2-level exclusive scan, scatter (e,src) by dst
__global__ void count_deg_kernel(const int* __restrict__ ei, int* __restrict__ deg) {
    int e = blockIdx.x * blockDim.x + threadIdx.x;
    if (e >= N_EDGES) return;
    atomicAdd(&deg[ei[N_EDGES + e]], 1);
}

__global__ void scan1_kernel(const int* __restrict__ deg,
                             int* __restrict__ rowptr, int* __restrict__ bsum) {
    __shared__ int sd[SCAN_B];
    int tid = threadIdx.x;
    int i = blockIdx.x * SCAN_B + tid;
    int v = (i < N_NODES) ? deg[i] : 0;
    sd[tid] = v;
    __syncthreads();
#pragma unroll
    for (int off = 1; off < SCAN_B; off <<= 1) {
        int tmp = (tid >= off) ? sd[tid - off] : 0;
        __syncthreads();
        sd[tid] += tmp;
        __syncthreads();
    }
    if (i < N_NODES) rowptr[i] = sd[tid] - v;
    if (tid == SCAN_B - 1) bsum[blockIdx.x] = sd[tid];
}

__global__ void scan2_kernel(const int* __restrict__ bsum, int* __restrict__ bscan) {
    __shared__ int sd[SCAN_B];
    int tid = threadIdx.x;
    int v = (tid < SCAN_NBLK) ? bsum[tid] : 0;
    sd[tid] = v;
    __syncthreads();
#pragma unroll
    for (int off = 1; off < SCAN_B; off <<= 1) {
        int tmp = (tid >= off) ? sd[tid - off] : 0;
        __syncthreads();
        sd[tid] += tmp;
        __syncthreads();
    }
    if (tid < SCAN_NBLK) bscan[tid] = sd[tid] - v;
}

__global__ void scan3_kernel(int* __restrict__ rowptr, const int* __restrict__ bscan) {
    int i = blockIdx.x * SCAN_B + threadIdx.x;
    if (i < N_NODES) rowptr[i] += bscan[blockIdx.x];
    if (i == 0) rowptr[N_NODES] = N_EDGES;
}

__global__ void fill_csr_kernel(const int* __restrict__ ei,
                                const int* __restrict__ rowptr,
                                int* __restrict__ cursor,
                                int2* __restrict__ srt) {
    int e = blockIdx.x * blockDim.x + threadIdx.x;
    if (e >= N_EDGES) return;
    int src = ei[e], dst = ei[N_EDGES + e];
    int pos = atomicAdd(&cursor[dst], 1);
    srt[rowptr[dst] + pos] = make_int2(e, src);
}

// ---------------------------------------------------------------------------
// Fused 4-projection bf16 MFMA GEMM: out_mat = hb @ W_mat + bias_mat.
// blockIdx.x -> 128-row tile (M_PAD/128=313), blockIdx.y -> mat (q,k,v,skip).
// 256 threads = 4 waves in 2x2; per-wave 64x64 via 4x4 grid of 16x16x32 MFMA.
// LDS: A[128][128] + Bt[128][128] bf16 = 64 KB, XOR-swizzled 16B granules
// (granule g of row r stored at g^(r&15)) -> only 2-way bank aliasing (free).
__global__ __launch_bounds__(256) void gemm_mfma(
    const bf16_t* __restrict__ hb, const bf16_t* __restrict__ Wt,
    const float* __restrict__ bq, const float* __restrict__ bk,
    const float* __restrict__ bv, const float* __restrict__ bs,
    float* __restrict__ qo, float* __restrict__ ko,
    float* __restrict__ vo, float* __restrict__ so) {
    __shared__ bf16_t Ash[128 * 128];
    __shared__ bf16_t Bsh[128 * 128];
    int tid = threadIdx.x;
    int mat = blockIdx.y;
    const bf16_t* W = Wt + (size_t)mat * HDIM * HDIM;
    const float* bias = (mat == 0) ? bq : (mat == 1) ? bk : (mat == 2) ? bv : bs;
    float* out = (mat == 0) ? qo : (mat == 1) ? ko : (mat == 2) ? vo : so;
    int row0 = blockIdx.x * 128;

    {   // stage A (node feats) and B (weight, already [n][k]) tiles
        int r = tid >> 4, g = tid & 15;
#pragma unroll
        for (int p = 0; p < 8; ++p) {
            int rr = p * 16 + r;
            int sw = (g ^ (rr & 15)) << 3;
            bf16x8 a = *(const bf16x8*)(hb + (size_t)(row0 + rr) * HDIM + g * 8);
            *(bf16x8*)(Ash + rr * 128 + sw) = a;
            bf16x8 bvec = *(const bf16x8*)(W + (size_t)rr * HDIM + g * 8);
            *(bf16x8*)(Bsh + rr * 128 + sw) = bvec;
        }
    }
    __syncthreads();

    int lane = tid & 63, wave = tid >> 6;
    int wr = (wave >> 1) * 64, wc = (wave & 1) * 64;
    int lm = lane & 15, quad = lane >> 4;

    f32x4 acc[4][4];
#pragma unroll
    for (int i = 0; i < 4; ++i)
#pragma unroll
        for (int j = 0; j < 4; ++j) acc[i][j] = (f32x4){0.f, 0.f, 0.f, 0.f};

#pragma unroll
    for (int ks = 0; ks < 4; ++ks) {
        int g = ks * 4 + quad;
        int sw = (g ^ lm) << 3;
        bf16x8 af[4], bf[4];
#pragma unroll
        for (int t = 0; t < 4; ++t) {
            int ar = wr + t * 16 + lm;   // ar & 15 == lm
            af[t] = *(const bf16x8*)(Ash + ar * 128 + sw);
            int br = wc + t * 16 + lm;
            bf[t] = *(const bf16x8*)(Bsh + br * 128 + sw);
        }
#pragma unroll
        for (int i = 0; i < 4; ++i)
#pragma unroll
            for (int j = 0; j < 4; ++j)
                acc[i][j] = __builtin_amdgcn_mfma_f32_16x16x32_bf16(af[i], bf[j], acc[i][j], 0, 0, 0);
    }

#pragma unroll
    for (int i = 0; i < 4; ++i) {
        int rbase = row0 + wr + i * 16 + quad * 4;
#pragma unroll
        for (int j = 0; j < 4; ++j) {
            int col = wc + j * 16 + lm;
            float bcol = bias[col];
#pragma unroll
            for (int r = 0; r < 4; ++r) {
                int row = rbase + r;
                if (row < N_NODES) out[(size_t)row * HDIM + col] = acc[i][j][r] + bcol;
            }
        }
    }
}

// ---------------------------------------------------------------------------
// Fused per-dst-node attention aggregation + skip + LayerNorm + ReLU.
// One block (128 threads = 2 waves) per node; thread t owns channel t.
__global__ __launch_bounds__(128) void agg_kernel(
    const int2* __restrict__ srt, const int* __restrict__ rowptr,
    const float* __restrict__ ea,
    const float* __restrict__ q, const float* __restrict__ k,
    const float* __restrict__ v,
    const float* __restrict__ Me, const float* __restrict__ ce,
    const float* __restrict__ skip,
    const float* __restrict__ lg, const float* __restrict__ lb,
    float* __restrict__ hout, bf16_t* __restrict__ hbout) {
    __shared__ float sMe[5 * HDIM];
    __shared__ float wred[2];
    int n = blockIdx.x;
    int t = threadIdx.x;
    for (int i = t; i < 5 * HDIM; i += 128) sMe[i] = Me[i];
    float cer = ce[t];
    float qv = q[(size_t)n * HDIM + t] * 0.17677669529663687f;  // fold 1/sqrt(C)
    __syncthreads();

    int beg = rowptr[n], end = rowptr[n + 1];
    float m = -INFINITY, l = 0.0f, o = 0.0f;
    for (int idx = beg; idx < end; ++idx) {
        int2 es = srt[idx];
        int e = es.x, src = es.y;
        float a0 = ea[e * 5 + 0], a1 = ea[e * 5 + 1], a2 = ea[e * 5 + 2];
        float a3 = ea[e * 5 + 3], a4 = ea[e * 5 + 4];
        float ev = cer + a0 * sMe[t] + a1 * sMe[HDIM + t] + a2 * sMe[2 * HDIM + t] +
                   a3 * sMe[3 * HDIM + t] + a4 * sMe[4 * HDIM + t];
        float kj = k[(size_t)src * HDIM + t] + ev;
        float p = qv * kj;
        p += __shfl_xor(p, 16, 32);
        p += __shfl_xor(p, 8, 32);
        p += __shfl_xor(p, 4, 32);
        p += __shfl_xor(p, 2, 32);
        p += __shfl_xor(p, 1, 32);
        float a = p;
        float m_new = fmaxf(m, a);
        float sc = __expf(m - m_new);
        float pe = __expf(a - m_new);
        float vj = v[(size_t)src * HDIM + t] + ev;
        o = o * sc + pe * vj;
        l = l * sc + pe;
        m = m_new;
    }
    float msg = o / (l + 1e-16f);
    float val = skip[(size_t)n * HDIM + t] + msg;

    float s = val;
#pragma unroll
    for (int mask = 32; mask >= 1; mask >>= 1) s += __shfl_xor(s, mask, 64);
    if ((t & 63) == 0) wred[t >> 6] = s;
    __syncthreads();
    float mu = (wred[0] + wred[1]) * (1.0f / HDIM);
    float d = val - mu;
    float s2 = d * d;
#pragma unroll
    for (int mask = 32; mask >= 1; mask >>= 1) s2 += __shfl_xor(s2, mask, 64);
    __syncthreads();
    if ((t & 63) == 0) wred[t >> 6] = s2;
    __syncthreads();
    float var = (wred[0] + wred[1]) * (1.0f / HDIM);
    float y = d * rsqrtf(var + 1e-5f) * lg[t] + lb[t];
    y = fmaxf(y, 0.0f);
    hout[(size_t)n * HDIM + t] = y;
    hbout[(size_t)n * HDIM + t] = (bf16_t)y;
}

// ---------------------------------------------------------------------------
// Chunked mean-pool: batch is sorted, so accumulate per-graph runs in
// registers and flush one atomicAdd per (graph-boundary, channel) per chunk.
__global__ __launch_bounds__(128) void pool_kernel(const float* __restrict__ h,
                                                   const int* __restrict__ batch,
                                                   float* __restrict__ pool,
                                                   float* __restrict__ cnt) {
    int t = threadIdx.x;
    int n0 = blockIdx.x * POOL_CHUNK;
    int n1 = n0 + POOL_CHUNK;
    if (n1 > N_NODES) n1 = N_NODES;
    int gcur = batch[n0];
    int cstart = n0;
    float acc = 0.0f;
    for (int n = n0; n < n1; ++n) {
        int g = batch[n];
        if (g != gcur) {  // block-uniform branch (batch sorted)
            atomicAdd(&pool[gcur * HDIM + t], acc);
            if (t == 0) atomicAdd(&cnt[gcur], (float)(n - cstart));
            acc = 0.0f;
            gcur = g;
            cstart = n;
        }
        acc += h[(size_t)n * HDIM + t];
    }
    atomicAdd(&pool[gcur * HDIM + t], acc);
    if (t == 0) atomicAdd(&cnt[gcur], (float)(n1 - cstart));
}

// ---------------------------------------------------------------------------
__global__ void heads_kernel(const float* __restrict__ pool,
                             const float* __restrict__ cnt,
                             const float* __restrict__ dw1, const float* __restrict__ db1,
                             const float* __restrict__ dw2, const float* __restrict__ db2,
                             const float* __restrict__ tw1, const float* __restrict__ tb1,
                             const float* __restrict__ tw2, const float* __restrict__ tb2,
                             float* __restrict__ outp) {
    int g = blockIdx.x, t = threadIdx.x;
    __shared__ float hg[HDIM];
    __shared__ float hid[64];
    float c = fmaxf(cnt[g], 1.0f);
    hg[t] = pool[g * HDIM + t] / c;
    __syncthreads();
    if (t < 64) {
        float s = db1[t];
        for (int i = 0; i < HDIM; ++i) s += hg[i] * dw1[i * 64 + t];
        hid[t] = fmaxf(s, 0.0f);
    }
    __syncthreads();
    if (t < ODIM) {
        float s = db2[t];
        for (int j = 0; j < 64; ++j) s += hid[j] * dw2[j * ODIM + t];
        outp[g * ODIM + t] = s;
    }
    __syncthreads();
    if (t < 64) {
        float s = tb1[t];
        for (int i = 0; i < HDIM; ++i) s += hg[i] * tw1[i * 64 + t];
        hid[t] = fmaxf(s, 0.0f);
    }
    __syncthreads();
    if (t < ODIM) {
        float s = tb2[t];
        for (int j = 0; j < 64; ++j) s += hid[j] * tw2[j * ODIM + t];
        outp[N_GRAPHS * ODIM + g * ODIM + t] = s;
    }
}

// ---------------------------------------------------------------------------
extern "C" void kernel_launch(void* const* d_in, const int* in_sizes, int n_in,
                              void* d_out, int out_size, void* d_ws, size_t ws_size,
                              hipStream_t stream) {
    const float* x        = (const float*)d_in[0];
    const float* ea       = (const float*)d_in[1];
    const float* node_w   = (const float*)d_in[2];
    const float* node_b   = (const float*)d_in[3];
    const float* edge_w   = (const float*)d_in[4];
    const float* edge_b   = (const float*)d_in[5];
    const float* Wq       = (const float*)d_in[6];
    const float* bq       = (const float*)d_in[7];
    const float* Wk       = (const float*)d_in[8];
    const float* bk       = (const float*)d_in[9];
    const float* Wv       = (const float*)d_in[10];
    const float* bv       = (const float*)d_in[11];
    const float* We       = (const float*)d_in[12];
    const float* Wskip    = (const float*)d_in[13];
    const float* bskip    = (const float*)d_in[14];
    const float* ln_g     = (const float*)d_in[15];
    const float* ln_b     = (const float*)d_in[16];
    const float* dw1      = (const float*)d_in[17];
    const float* db1      = (const float*)d_in[18];
    const float* dw2      = (const float*)d_in[19];
    const float* db2      = (const float*)d_in[20];
    const float* tw1      = (const float*)d_in[21];
    const float* tb1      = (const float*)d_in[22];
    const float* tw2      = (const float*)d_in[23];
    const float* tb2      = (const float*)d_in[24];
    const int*   ei       = (const int*)d_in[25];
    const int*   batch    = (const int*)d_in[26];
    float* out = (float*)d_out;
    (void)in_sizes; (void)n_in; (void)out_size; (void)ws_size;

    // ---- workspace carve (256B aligned) ----
    char* wsb = (char*)d_ws;
    size_t off = 0;
    auto carve = [&](size_t bytes) -> void* {
        void* p = wsb + off;
        off += (bytes + 255) & ~(size_t)255;
        return p;
    };
    float*  h      = (float*) carve((size_t)N_NODES * HDIM * 4);
    bf16_t* hbuf   = (bf16_t*)carve((size_t)M_PAD * HDIM * 2);
    float*  q      = (float*) carve((size_t)N_NODES * HDIM * 4);
    float*  k      = (float*) carve((size_t)N_NODES * HDIM * 4);
    float*  v      = (float*) carve((size_t)N_NODES * HDIM * 4);
    float*  ob     = (float*) carve((size_t)N_NODES * HDIM * 4);   // skip buffer
    bf16_t* Wtb    = (bf16_t*)carve((size_t)NLAYERS * 4 * HDIM * HDIM * 2);
    int2*   srt    = (int2*)  carve((size_t)N_EDGES * 8);
    int*    deg    = (int*)   carve((size_t)N_NODES * 4);
    int*    rowptr = (int*)   carve((size_t)(N_NODES + 1) * 4);
    int*    cursor = (int*)   carve((size_t)N_NODES * 4);
    int*    bsum   = (int*)   carve((size_t)SCAN_NBLK * 4);
    int*    bscan  = (int*)   carve((size_t)SCAN_NBLK * 4);
    float*  Me_all = (float*) carve((size_t)NLAYERS * 5 * HDIM * 4);
    float*  ce_all = (float*) carve((size_t)NLAYERS * HDIM * 4);
    float*  pool   = (float*) carve((size_t)N_GRAPHS * HDIM * 4);
    float*  cnt    = (float*) carve((size_t)N_GRAPHS * 4);

    const int nthreads = 256;
    const int e_blocks  = (N_EDGES + nthreads - 1) / nthreads;
    const int nc_blocks = (N_NODES * HDIM) / nthreads;

    // ---- CSR build ----
    hipMemsetAsync(deg, 0, (size_t)N_NODES * 4, stream);
    hipMemsetAsync(cursor, 0, (size_t)N_NODES * 4, stream);
    count_deg_kernel<<<e_blocks, nthreads, 0, stream>>>(ei, deg);
    scan1_kernel<<<SCAN_NBLK, SCAN_B, 0, stream>>>(deg, rowptr, bsum);
    scan2_kernel<<<1, SCAN_B, 0, stream>>>(bsum, bscan);
    scan3_kernel<<<SCAN_NBLK, SCAN_B, 0, stream>>>(rowptr, bscan);
    fill_csr_kernel<<<e_blocks, nthreads, 0, stream>>>(ei, rowptr, cursor, srt);

    // ---- projections / weight prep ----
    hipMemsetAsync(hbuf + (size_t)N_NODES * HDIM, 0,
                   (size_t)(M_PAD - N_NODES) * HDIM * 2, stream);  // zero pad rows
    nodeproj_kernel<<<nc_blocks, nthreads, 0, stream>>>(x, node_w, node_b, h, hbuf);
    fold_edge_kernel<<<NLAYERS * 6, HDIM, 0, stream>>>(edge_w, edge_b, We, Me_all, ce_all);
    convert_w_kernel<<<NLAYERS * 4 * HDIM, HDIM, 0, stream>>>(Wq, Wk, Wv, Wskip, Wtb);

    for (int i = 0; i < NLAYERS; ++i) {
        const float* Me = Me_all + i * 5 * HDIM;
        const float* ce = ce_all + i * HDIM;
        gemm_mfma<<<dim3(M_PAD / 128, 4), 256, 0, stream>>>(
            hbuf, Wtb + (size_t)i * 4 * HDIM * HDIM,
            bq + i * HDIM, bk + i * HDIM, bv + i * HDIM, bskip + i * HDIM,
            q, k, v, ob);
        agg_kernel<<<N_NODES, 128, 0, stream>>>(srt, rowptr, ea, q, k, v, Me, ce, ob,
                                                ln_g + i * HDIM, ln_b + i * HDIM, h, hbuf);
    }

    hipMemsetAsync(pool, 0, (size_t)N_GRAPHS * HDIM * 4, stream);
    hipMemsetAsync(cnt, 0, (size_t)N_GRAPHS * 4, stream);
    pool_kernel<<<POOL_NBLK, HDIM, 0, stream>>>(h, batch, pool, cnt);
    heads_kernel<<<N_GRAPHS, HDIM, 0, stream>>>(pool, cnt, dw1, db1, dw2, db2,
                                                tw1, tb1, tw2, tb2, out);
}